// Round 1
// baseline (4871.386 us; speedup 1.0000x reference)
//
#include <hip/hip_runtime.h>
#include <stdint.h>

#define T_STEPS 256
#define BATCH   32
#define DIN     4096
#define HD      512
#define NREL    51
#define TB      8192      // T*B
#define SIXH    3072
#define FIVEH   2560

typedef short bf16x8 __attribute__((ext_vector_type(8)));
typedef float f32x4  __attribute__((ext_vector_type(4)));

typedef __attribute__((address_space(1))) const void gvoid_t;
typedef __attribute__((address_space(3))) void lvoid_t;

__device__ inline float bf2f(unsigned short u) {
    return __uint_as_float(((unsigned int)u) << 16);
}
__device__ inline unsigned short f2bf(float f) {
    unsigned int x = __float_as_uint(f);
    x += 0x7fffu + ((x >> 16) & 1u);   // RNE
    return (unsigned short)(x >> 16);
}
__device__ inline float sigm(float x) { return 1.f / (1.f + expf(-x)); }

__device__ inline void gll16(const void* g, void* l) {
    __builtin_amdgcn_global_load_lds((gvoid_t*)g, (lvoid_t*)l, 16, 0, 0);
}

// ---------- phase 0: converts / init ----------
__global__ void k_cvt(const float* __restrict__ s, unsigned short* __restrict__ d, int n4) {
    int i = blockIdx.x * blockDim.x + threadIdx.x;
    int st = gridDim.x * blockDim.x;
    for (; i < n4; i += st) {
        float4 v = ((const float4*)s)[i];
        ushort4 o;
        o.x = f2bf(v.x); o.y = f2bf(v.y); o.z = f2bf(v.z); o.w = f2bf(v.w);
        ((ushort4*)d)[i] = o;
    }
}

__global__ void k_split(const float* __restrict__ s, unsigned short* __restrict__ dh,
                        unsigned short* __restrict__ dl, int n4) {
    int i = blockIdx.x * blockDim.x + threadIdx.x;
    int st = gridDim.x * blockDim.x;
    for (; i < n4; i += st) {
        float4 v = ((const float4*)s)[i];
        ushort4 oh, ol;
        oh.x = f2bf(v.x); ol.x = f2bf(v.x - bf2f(oh.x));
        oh.y = f2bf(v.y); ol.y = f2bf(v.y - bf2f(oh.y));
        oh.z = f2bf(v.z); ol.z = f2bf(v.z - bf2f(oh.z));
        oh.w = f2bf(v.w); ol.w = f2bf(v.w - bf2f(oh.w));
        ((ushort4*)dh)[i] = oh;
        ((ushort4*)dl)[i] = ol;
    }
}

__global__ void k_init(const float* __restrict__ h0, const float* __restrict__ c0,
                       float* __restrict__ mh, float* __restrict__ mc, int n) {
    int i = blockIdx.x * blockDim.x + threadIdx.x;
    int st = gridDim.x * blockDim.x;
    for (; i < n; i += st) { mh[i] = h0[i]; mc[i] = c0[i]; }
}

// ---------- phase 1: PI = x @ W_in^T + b_in  (bf16 MFMA, m97 structure) ----------
__global__ __launch_bounds__(256) void k_gemm_pi(const unsigned short* __restrict__ xb,
                                                 const unsigned short* __restrict__ wb,
                                                 const float* __restrict__ bin,
                                                 unsigned short* __restrict__ PI) {
    __shared__ unsigned short sA[128 * 32];
    __shared__ unsigned short sB[128 * 32];
    const int tid = threadIdx.x;
    const int w = tid >> 6, l = tid & 63;
    const int wr = w >> 1, wc = w & 1;
    const long brow = (long)blockIdx.y * 128;
    const long bcol = (long)blockIdx.x * 128;

    f32x4 acc[4][4] = {};

    const int c0 = w * 128 + l;              // chunk (16B units) for sub-load 0
    const int r0 = c0 >> 2, kc0 = (c0 & 3) * 8;
    const int c1 = c0 + 64;
    const int r1 = c1 >> 2, kc1 = (c1 & 3) * 8;
    unsigned short* lds0A = sA + (w * 128) * 8;        // wave-uniform LDS bases
    unsigned short* lds1A = sA + (w * 128 + 64) * 8;
    unsigned short* lds0B = sB + (w * 128) * 8;
    unsigned short* lds1B = sB + (w * 128 + 64) * 8;

    const int frow = l & 15, kg = (l >> 4) * 8;

    for (int k0 = 0; k0 < DIN; k0 += 32) {
        __syncthreads();   // prev-iter readers done
        gll16(xb + (brow + r0) * DIN + k0 + kc0, lds0A);
        gll16(xb + (brow + r1) * DIN + k0 + kc1, lds1A);
        gll16(wb + (bcol + r0) * DIN + k0 + kc0, lds0B);
        gll16(wb + (bcol + r1) * DIN + k0 + kc1, lds1B);
        __syncthreads();   // vmcnt drained by compiler before barrier
        bf16x8 aF[4], bF[4];
#pragma unroll
        for (int m = 0; m < 4; ++m)
            aF[m] = *(const bf16x8*)(sA + (wr * 64 + m * 16 + frow) * 32 + kg);
#pragma unroll
        for (int n = 0; n < 4; ++n)
            bF[n] = *(const bf16x8*)(sB + (wc * 64 + n * 16 + frow) * 32 + kg);
#pragma unroll
        for (int m = 0; m < 4; ++m)
#pragma unroll
            for (int n = 0; n < 4; ++n)
                acc[m][n] = __builtin_amdgcn_mfma_f32_16x16x32_bf16(aF[m], bF[n], acc[m][n], 0, 0, 0);
    }

#pragma unroll
    for (int m = 0; m < 4; ++m) {
#pragma unroll
        for (int n = 0; n < 4; ++n) {
            const long col = bcol + wc * 64 + n * 16 + (l & 15);
            const float bv = bin[col];
#pragma unroll
            for (int r = 0; r < 4; ++r) {
                const long row = brow + wr * 64 + m * 16 + (l >> 4) * 4 + r;
                PI[row * SIXH + col] = f2bf(acc[m][n][r] + bv);
            }
        }
    }
}

// ---------- phase 2: one recurrent step ----------
// Grid 32 WGs x 256 thr. WG j owns h-columns [16j, 16j+16). Split-bf16 (hi+lo)
// for both h and W_state => ps is fp32-grade. States fp32, ping-pong buffers.
__global__ __launch_bounds__(256) void k_step(const int* __restrict__ rel,
                                              const unsigned short* __restrict__ PI,
                                              const unsigned short* __restrict__ wsh,
                                              const unsigned short* __restrict__ wsl,
                                              const float* __restrict__ bst,
                                              const float* __restrict__ drop,
                                              const float* __restrict__ mhs,
                                              const float* __restrict__ mcs,
                                              float* __restrict__ mhd,
                                              float* __restrict__ mcd,
                                              float* __restrict__ Hs, int t) {
    __shared__ unsigned short hh[BATCH * HD];   // 32 KB, XOR-swizzled
    __shared__ unsigned short hl[BATCH * HD];   // 32 KB
    __shared__ float red[2][5][256];            // kh=1 partials: [m][g][lane*4+r]

    const int tid = threadIdx.x;
    const int w = tid >> 6, l = tid & 63;
    const int hc0 = blockIdx.x * 16;

    // 1) carry forward all relation states for this WG's column slice
    for (int i = tid; i < NREL * 16; i += 256) {
        const int rr = i >> 4, cc = hc0 + (i & 15);
        mhd[rr * HD + cc] = mhs[rr * HD + cc];
        mcd[rr * HD + cc] = mcs[rr * HD + cc];
    }

    // 2) gather h_prev rows, split to bf16 hi/lo, swizzled LDS store
    {
        const int row = tid >> 3, seg = tid & 7;
        const int id = rel[t * BATCH + row];
        const float* hp = mhs + id * HD;
        const int rowb = row * 1024;
        const int sw = (row & 7) << 4;
#pragma unroll
        for (int it = 0; it < 16; ++it) {
            const int col = seg * 64 + it * 4;
            float4 v = *(const float4*)(hp + col);
            ushort4 vh, vl;
            vh.x = f2bf(v.x); vl.x = f2bf(v.x - bf2f(vh.x));
            vh.y = f2bf(v.y); vl.y = f2bf(v.y - bf2f(vh.y));
            vh.z = f2bf(v.z); vl.z = f2bf(v.z - bf2f(vh.z));
            vh.w = f2bf(v.w); vl.w = f2bf(v.w - bf2f(vh.w));
            const int byte = (rowb + col * 2) ^ sw;
            *(ushort4*)((char*)hh + byte) = vh;
            *(ushort4*)((char*)hl + byte) = vl;
        }
    }
    __syncthreads();

    // 3) ps GEMM: wave -> (m = b-half, kh = k-half); 5 gates; split-bf16 (3 MFMA)
    const int m = w & 1, kh = w >> 1;
    f32x4 acc[5] = {};
    const int arow = m * 16 + (l & 15);
    const int rb = arow * 1024, asw = (arow & 7) << 4;
    const int bcol = hc0 + (l & 15);
    for (int kk = 0; kk < 8; ++kk) {
        const int k = kh * 256 + kk * 32 + (l >> 4) * 8;
        const int ab = (rb + k * 2) ^ asw;
        const bf16x8 ah = *(const bf16x8*)((const char*)hh + ab);
        const bf16x8 al = *(const bf16x8*)((const char*)hl + ab);
#pragma unroll
        for (int g = 0; g < 5; ++g) {
            const size_t wo = (size_t)(g * HD + bcol) * HD + k;
            const bf16x8 bh = *(const bf16x8*)(wsh + wo);
            const bf16x8 bl = *(const bf16x8*)(wsl + wo);
            acc[g] = __builtin_amdgcn_mfma_f32_16x16x32_bf16(ah, bh, acc[g], 0, 0, 0);
            acc[g] = __builtin_amdgcn_mfma_f32_16x16x32_bf16(al, bh, acc[g], 0, 0, 0);
            acc[g] = __builtin_amdgcn_mfma_f32_16x16x32_bf16(ah, bl, acc[g], 0, 0, 0);
        }
    }
    if (kh == 1) {
#pragma unroll
        for (int g = 0; g < 5; ++g) *(f32x4*)&red[m][g][l * 4] = acc[g];
    }
    __syncthreads();

    // 4) gates + scatter (waves 0,1 only; m == w)
    if (w < 2) {
        float ps[5][4];
#pragma unroll
        for (int g = 0; g < 5; ++g) {
            const f32x4 s1 = *(const f32x4*)&red[w][g][l * 4];
#pragma unroll
            for (int r = 0; r < 4; ++r) ps[g][r] = acc[g][r] + s1[r];
        }
        const int col = hc0 + (l & 15);
        const float bs0 = bst[col], bs1 = bst[HD + col], bs2 = bst[2 * HD + col];
        const float bs3 = bst[3 * HD + col], bs4 = bst[4 * HD + col];
#pragma unroll
        for (int r = 0; r < 4; ++r) {
            const int b = w * 16 + (l >> 4) * 4 + r;
            const int grow = t * BATCH + b;
            const int id = rel[grow];
            const unsigned short* pr = PI + (size_t)grow * SIXH;
            const float pii = bf2f(pr[col]);
            const float pif = bf2f(pr[HD + col]);
            const float pig = bf2f(pr[2 * HD + col]);
            const float pio = bf2f(pr[3 * HD + col]);
            const float piw = bf2f(pr[4 * HD + col]);
            const float pip = bf2f(pr[5 * HD + col]);
            const float ig = sigm(pii + ps[0][r] + bs0);
            const float fg = sigm(pif + ps[1][r] + bs1);
            const float gg = tanhf(pig + ps[2][r] + bs2);
            const float og = sigm(pio + ps[3][r] + bs3);
            const float hw = sigm(piw + ps[4][r] + bs4);
            const float cp = mcs[id * HD + col];
            const float cn = ig * gg + fg * cp;
            float h = og * tanhf(cn);
            h = hw * h + (1.f - hw) * pip;
            h *= drop[b * HD + col];
            mcd[id * HD + col] = cn;
            mhd[id * HD + col] = h;
            Hs[(size_t)grow * HD + col] = h;
        }
    }
}

// ---------- phase 3: preds = Hsave @ W_out^T + b_out (fp32) ----------
__global__ __launch_bounds__(256) void k_pred(const float* __restrict__ Hs,
                                              const float* __restrict__ Wout,
                                              const float* __restrict__ bout,
                                              float* __restrict__ out) {
    __shared__ float hT[16 * HD];
    const int tid = threadIdx.x;
    const long row0 = (long)blockIdx.x * 16;
    for (int i = tid; i < (16 * HD) / 4; i += 256)
        ((float4*)hT)[i] = ((const float4*)(Hs + row0 * HD))[i];
    __syncthreads();
    const int w = tid >> 6, c = tid & 63;
    if (c < NREL) {
        float a0 = bout[c], a1 = a0, a2 = a0, a3 = a0;
        const float* wrp = Wout + c * HD;
        for (int k = 0; k < HD; k += 4) {
            const float4 wv = *(const float4*)(wrp + k);
            const float4 h0 = *(const float4*)(hT + (w * 4 + 0) * HD + k);
            const float4 h1 = *(const float4*)(hT + (w * 4 + 1) * HD + k);
            const float4 h2 = *(const float4*)(hT + (w * 4 + 2) * HD + k);
            const float4 h3 = *(const float4*)(hT + (w * 4 + 3) * HD + k);
            a0 += wv.x * h0.x + wv.y * h0.y + wv.z * h0.z + wv.w * h0.w;
            a1 += wv.x * h1.x + wv.y * h1.y + wv.z * h1.z + wv.w * h1.w;
            a2 += wv.x * h2.x + wv.y * h2.y + wv.z * h2.z + wv.w * h2.w;
            a3 += wv.x * h3.x + wv.y * h3.y + wv.z * h3.z + wv.w * h3.w;
        }
        out[(row0 + w * 4 + 0) * NREL + c] = a0;
        out[(row0 + w * 4 + 1) * NREL + c] = a1;
        out[(row0 + w * 4 + 2) * NREL + c] = a2;
        out[(row0 + w * 4 + 3) * NREL + c] = a3;
    }
}

extern "C" void kernel_launch(void* const* d_in, const int* in_sizes, int n_in,
                              void* d_out, int out_size, void* d_ws, size_t ws_size,
                              hipStream_t stream) {
    const float* x    = (const float*)d_in[0];
    const int*   rel  = (const int*)  d_in[1];
    const float* h0   = (const float*)d_in[2];
    const float* c0   = (const float*)d_in[3];
    const float* Win  = (const float*)d_in[4];
    const float* bin  = (const float*)d_in[5];
    const float* Wst  = (const float*)d_in[6];
    const float* bst  = (const float*)d_in[7];
    const float* Wout = (const float*)d_in[8];
    const float* bout = (const float*)d_in[9];
    const float* drop = (const float*)d_in[10];

    char* ws = (char*)d_ws;
    // workspace layout (bytes), total 165,044,224
    unsigned short* xb  = (unsigned short*)(ws);              // 67,108,864
    unsigned short* wb  = (unsigned short*)(ws + 67108864);   // 25,165,824
    unsigned short* wsh = (unsigned short*)(ws + 92274688);   //  2,621,440
    unsigned short* wsl = (unsigned short*)(ws + 94896128);   //  2,621,440
    float*          mh  = (float*)(ws + 97517568);            //  2 x 104,448
    float*          mc  = (float*)(ws + 97726464);            //  2 x 104,448
    float*          Hs  = (float*)(ws + 97935360);            // 16,777,216
    unsigned short* PI  = (unsigned short*)(ws + 114712576);  // 50,331,648
    float* out = (float*)d_out;

    k_cvt<<<2048, 256, 0, stream>>>(x, xb, (TB * DIN) / 4);
    k_cvt<<<1024, 256, 0, stream>>>(Win, wb, (SIXH * DIN) / 4);
    k_split<<<320, 256, 0, stream>>>(Wst, wsh, wsl, (FIVEH * HD) / 4);
    k_init<<<102, 256, 0, stream>>>(h0, c0, mh, mc, NREL * HD);

    k_gemm_pi<<<dim3(SIXH / 128, TB / 128), 256, 0, stream>>>(xb, wb, bin, PI);

    for (int t = 0; t < T_STEPS; ++t) {
        const int s = t & 1, d = s ^ 1;
        k_step<<<32, 256, 0, stream>>>(rel, PI, wsh, wsl, bst, drop,
                                       mh + s * (NREL * HD), mc + s * (NREL * HD),
                                       mh + d * (NREL * HD), mc + d * (NREL * HD),
                                       Hs, t);
    }
    k_pred<<<512, 256, 0, stream>>>(Hs, Wout, bout, out);
}

// Round 2
// 3375.432 us; speedup vs baseline: 1.4432x; 1.4432x over previous
//
#include <hip/hip_runtime.h>
#include <hip/hip_cooperative_groups.h>
#include <stdint.h>

namespace cg = cooperative_groups;

#define T_STEPS 256
#define BATCH   32
#define DIN     4096
#define HD      512
#define NREL    51
#define TB      8192      // T*B
#define SIXH    3072
#define FIVEH   2560
#define SREL    (NREL * HD)

typedef short bf16x8 __attribute__((ext_vector_type(8)));
typedef float f32x4  __attribute__((ext_vector_type(4)));

typedef __attribute__((address_space(1))) const void gvoid_t;
typedef __attribute__((address_space(3))) void lvoid_t;

__device__ inline float bf2f(unsigned short u) {
    return __uint_as_float(((unsigned int)u) << 16);
}
__device__ inline unsigned short f2bf(float f) {
    unsigned int x = __float_as_uint(f);
    x += 0x7fffu + ((x >> 16) & 1u);   // RNE
    return (unsigned short)(x >> 16);
}
__device__ inline float sigm(float x) { return 1.f / (1.f + expf(-x)); }

__device__ inline void gll16(const void* g, void* l) {
    __builtin_amdgcn_global_load_lds((gvoid_t*)g, (lvoid_t*)l, 16, 0, 0);
}

// ---------- phase 0: fp32 -> bf16 converts ----------
__global__ void k_cvt(const float* __restrict__ s, unsigned short* __restrict__ d, int n4) {
    int i = blockIdx.x * blockDim.x + threadIdx.x;
    int st = gridDim.x * blockDim.x;
    for (; i < n4; i += st) {
        float4 v = ((const float4*)s)[i];
        ushort4 o;
        o.x = f2bf(v.x); o.y = f2bf(v.y); o.z = f2bf(v.z); o.w = f2bf(v.w);
        ((ushort4*)d)[i] = o;
    }
}

// ---------- phase 1: PI = x @ W_in^T + b_in  (bf16 MFMA, m97 structure) ----------
__global__ __launch_bounds__(256) void k_gemm_pi(const unsigned short* __restrict__ xb,
                                                 const unsigned short* __restrict__ wb,
                                                 const float* __restrict__ bin,
                                                 unsigned short* __restrict__ PI) {
    __shared__ unsigned short sA[128 * 32];
    __shared__ unsigned short sB[128 * 32];
    const int tid = threadIdx.x;
    const int w = tid >> 6, l = tid & 63;
    const int wr = w >> 1, wc = w & 1;
    const long brow = (long)blockIdx.y * 128;
    const long bcol = (long)blockIdx.x * 128;

    f32x4 acc[4][4] = {};

    const int c0 = w * 128 + l;
    const int r0 = c0 >> 2, kc0 = (c0 & 3) * 8;
    const int c1 = c0 + 64;
    const int r1 = c1 >> 2, kc1 = (c1 & 3) * 8;
    unsigned short* lds0A = sA + (w * 128) * 8;
    unsigned short* lds1A = sA + (w * 128 + 64) * 8;
    unsigned short* lds0B = sB + (w * 128) * 8;
    unsigned short* lds1B = sB + (w * 128 + 64) * 8;

    const int frow = l & 15, kg = (l >> 4) * 8;

    for (int k0 = 0; k0 < DIN; k0 += 32) {
        __syncthreads();
        gll16(xb + (brow + r0) * DIN + k0 + kc0, lds0A);
        gll16(xb + (brow + r1) * DIN + k0 + kc1, lds1A);
        gll16(wb + (bcol + r0) * DIN + k0 + kc0, lds0B);
        gll16(wb + (bcol + r1) * DIN + k0 + kc1, lds1B);
        __syncthreads();
        bf16x8 aF[4], bF[4];
#pragma unroll
        for (int m = 0; m < 4; ++m)
            aF[m] = *(const bf16x8*)(sA + (wr * 64 + m * 16 + frow) * 32 + kg);
#pragma unroll
        for (int n = 0; n < 4; ++n)
            bF[n] = *(const bf16x8*)(sB + (wc * 64 + n * 16 + frow) * 32 + kg);
#pragma unroll
        for (int m = 0; m < 4; ++m)
#pragma unroll
            for (int n = 0; n < 4; ++n)
                acc[m][n] = __builtin_amdgcn_mfma_f32_16x16x32_bf16(aF[m], bF[n], acc[m][n], 0, 0, 0);
    }

#pragma unroll
    for (int m = 0; m < 4; ++m) {
#pragma unroll
        for (int n = 0; n < 4; ++n) {
            const long col = bcol + wc * 64 + n * 16 + (l & 15);
            const float bv = bin[col];
#pragma unroll
            for (int r = 0; r < 4; ++r) {
                const long row = brow + wr * 64 + m * 16 + (l >> 4) * 4 + r;
                PI[row * SIXH + col] = f2bf(acc[m][n][r] + bv);
            }
        }
    }
}

// ---------- phase 2: persistent recurrence (cooperative, 32 WGs) ----------
// WG j owns h-columns [16j,16j+16). W_state-hi slice lives in LDS (swizzled)
// for all 256 steps. State = (bf16-hi, bf16-lo, fp32 c), ping-pong buffers,
// one grid.sync per step.
__global__ __launch_bounds__(256) void k_recur(
    const int* __restrict__ rel, const float* __restrict__ h0,
    const float* __restrict__ c0, const unsigned short* __restrict__ PI,
    const unsigned short* __restrict__ wsb, const float* __restrict__ bst,
    const float* __restrict__ drop, unsigned short* __restrict__ mhh,
    unsigned short* __restrict__ mhl, float* __restrict__ mcb,
    float* __restrict__ Hs)
{
    cg::grid_group grid = cg::this_grid();
    __shared__ unsigned short Wl[5 * 16 * 512];   // 80 KB, XOR-swizzled
    __shared__ float red[2][5][256];              // 10 KB kh=1 partials
    __shared__ int relS[T_STEPS * BATCH];         // 32 KB

    const int tid = threadIdx.x;
    const int w = tid >> 6, l = tid & 63;
    const int hc0 = blockIdx.x * 16;

    for (int i = tid; i < T_STEPS * BATCH; i += 256) relS[i] = rel[i];

    // stage W_state-hi slice into LDS, swizzled: byte ^= (col&7)<<4
    for (int i = tid; i < (5 * 16 * 512) / 8; i += 256) {
        const int k8 = i & 63, gc = i >> 6, c = gc & 15, g = gc >> 4;
        const bf16x8 v = *(const bf16x8*)(wsb + (size_t)(g * HD + hc0 + c) * HD + k8 * 8);
        const int byte = ((gc * 512 + k8 * 8) * 2) ^ ((c & 7) << 4);
        *(bf16x8*)((char*)Wl + byte) = v;
    }

    // init state buffer 0 for this WG's column slice
    for (int i = tid; i < NREL * 16; i += 256) {
        const int idx = (i >> 4) * HD + hc0 + (i & 15);
        const float hv = h0[idx];
        const unsigned short hi = f2bf(hv);
        mhh[idx] = hi;
        mhl[idx] = f2bf(hv - bf2f(hi));
        mcb[idx] = c0[idx];
    }

    const int m = w & 1, kh = w >> 1;
    const int col = hc0 + (l & 15);
    float bs0 = 0, bs1 = 0, bs2 = 0, bs3 = 0, bs4 = 0;
    float dropv[4] = {};
    if (w < 2) {
        bs0 = bst[col]; bs1 = bst[HD + col]; bs2 = bst[2 * HD + col];
        bs3 = bst[3 * HD + col]; bs4 = bst[4 * HD + col];
#pragma unroll
        for (int r = 0; r < 4; ++r)
            dropv[r] = drop[(w * 16 + (l >> 4) * 4 + r) * HD + col];
    }
    __syncthreads();
    grid.sync();

    for (int t = 0; t < T_STEPS; ++t) {
        const int s = t & 1;
        const unsigned short* hhs = mhh + s * SREL;
        const unsigned short* hls = mhl + s * SREL;
        const float*          mcs = mcb + s * SREL;
        unsigned short* hhd = mhh + (s ^ 1) * SREL;
        unsigned short* hld = mhl + (s ^ 1) * SREL;
        float*          mcd = mcb + (s ^ 1) * SREL;

        // carry forward this WG's column slice (all relations)
        for (int i = tid; i < NREL * 16; i += 256) {
            const int idx = (i >> 4) * HD + hc0 + (i & 15);
            hhd[idx] = hhs[idx];
            hld[idx] = hls[idx];
            mcd[idx] = mcs[idx];
        }

        // gather A fragments straight from global state (hi+lo)
        const int brow = m * 16 + (l & 15);
        const int id = relS[t * BATCH + brow];
        const unsigned short* hr = hhs + (size_t)id * HD + kh * 256 + (l >> 4) * 8;
        const unsigned short* lr = hls + (size_t)id * HD + kh * 256 + (l >> 4) * 8;
        bf16x8 ah[8], al[8];
#pragma unroll
        for (int kk = 0; kk < 8; ++kk) {
            ah[kk] = *(const bf16x8*)(hr + kk * 32);
            al[kk] = *(const bf16x8*)(lr + kk * 32);
        }

        f32x4 acc[5] = {};
#pragma unroll
        for (int kk = 0; kk < 8; ++kk) {
            const int kb2 = (kh * 256 + kk * 32 + (l >> 4) * 8) * 2;
#pragma unroll
            for (int g = 0; g < 5; ++g) {
                const int byte = (((g * 16 + (l & 15)) * 1024) + kb2) ^ ((l & 7) << 4);
                const bf16x8 bh = *(const bf16x8*)((const char*)Wl + byte);
                acc[g] = __builtin_amdgcn_mfma_f32_16x16x32_bf16(ah[kk], bh, acc[g], 0, 0, 0);
                acc[g] = __builtin_amdgcn_mfma_f32_16x16x32_bf16(al[kk], bh, acc[g], 0, 0, 0);
            }
        }

        if (kh == 1) {
#pragma unroll
            for (int g = 0; g < 5; ++g) *(f32x4*)&red[m][g][l * 4] = acc[g];
        }
        __syncthreads();

        if (w < 2) {
            float ps[5][4];
#pragma unroll
            for (int g = 0; g < 5; ++g) {
                const f32x4 s1 = *(const f32x4*)&red[w][g][l * 4];
#pragma unroll
                for (int r = 0; r < 4; ++r) ps[g][r] = acc[g][r] + s1[r];
            }
#pragma unroll
            for (int r = 0; r < 4; ++r) {
                const int b = w * 16 + (l >> 4) * 4 + r;
                const int grow = t * BATCH + b;
                const int id2 = relS[grow];
                const unsigned short* pr = PI + (size_t)grow * SIXH;
                const float pii = bf2f(pr[col]);
                const float pif = bf2f(pr[HD + col]);
                const float pig = bf2f(pr[2 * HD + col]);
                const float pio = bf2f(pr[3 * HD + col]);
                const float piw = bf2f(pr[4 * HD + col]);
                const float pip = bf2f(pr[5 * HD + col]);
                const float ig = sigm(pii + ps[0][r] + bs0);
                const float fg = sigm(pif + ps[1][r] + bs1);
                const float gg = tanhf(pig + ps[2][r] + bs2);
                const float og = sigm(pio + ps[3][r] + bs3);
                const float hw = sigm(piw + ps[4][r] + bs4);
                const float cp = mcs[(size_t)id2 * HD + col];
                const float cn = ig * gg + fg * cp;
                float h = og * tanhf(cn);
                h = hw * h + (1.f - hw) * pip;
                h *= dropv[r];
                mcd[(size_t)id2 * HD + col] = cn;
                const unsigned short hhi = f2bf(h);
                hhd[(size_t)id2 * HD + col] = hhi;
                hld[(size_t)id2 * HD + col] = f2bf(h - bf2f(hhi));
                Hs[(size_t)grow * HD + col] = h;
            }
        }
        grid.sync();
    }
}

// ---------- phase 3: preds = Hs @ W_out^T + b_out (fp32) ----------
__global__ __launch_bounds__(256) void k_pred(const float* __restrict__ Hs,
                                              const float* __restrict__ Wout,
                                              const float* __restrict__ bout,
                                              float* __restrict__ out) {
    __shared__ float hT[16 * HD];
    const int tid = threadIdx.x;
    const long row0 = (long)blockIdx.x * 16;
    for (int i = tid; i < (16 * HD) / 4; i += 256)
        ((float4*)hT)[i] = ((const float4*)(Hs + row0 * HD))[i];
    __syncthreads();
    const int w = tid >> 6, c = tid & 63;
    if (c < NREL) {
        float a0 = bout[c], a1 = a0, a2 = a0, a3 = a0;
        const float* wrp = Wout + c * HD;
        for (int k = 0; k < HD; k += 4) {
            const float4 wv = *(const float4*)(wrp + k);
            const float4 h0 = *(const float4*)(hT + (w * 4 + 0) * HD + k);
            const float4 h1 = *(const float4*)(hT + (w * 4 + 1) * HD + k);
            const float4 h2 = *(const float4*)(hT + (w * 4 + 2) * HD + k);
            const float4 h3 = *(const float4*)(hT + (w * 4 + 3) * HD + k);
            a0 += wv.x * h0.x + wv.y * h0.y + wv.z * h0.z + wv.w * h0.w;
            a1 += wv.x * h1.x + wv.y * h1.y + wv.z * h1.z + wv.w * h1.w;
            a2 += wv.x * h2.x + wv.y * h2.y + wv.z * h2.z + wv.w * h2.w;
            a3 += wv.x * h3.x + wv.y * h3.y + wv.z * h3.z + wv.w * h3.w;
        }
        out[(row0 + w * 4 + 0) * NREL + c] = a0;
        out[(row0 + w * 4 + 1) * NREL + c] = a1;
        out[(row0 + w * 4 + 2) * NREL + c] = a2;
        out[(row0 + w * 4 + 3) * NREL + c] = a3;
    }
}

extern "C" void kernel_launch(void* const* d_in, const int* in_sizes, int n_in,
                              void* d_out, int out_size, void* d_ws, size_t ws_size,
                              hipStream_t stream) {
    const float* x    = (const float*)d_in[0];
    const int*   rel  = (const int*)  d_in[1];
    const float* h0   = (const float*)d_in[2];
    const float* c0   = (const float*)d_in[3];
    const float* Win  = (const float*)d_in[4];
    const float* bin  = (const float*)d_in[5];
    const float* Wst  = (const float*)d_in[6];
    const float* bst  = (const float*)d_in[7];
    const float* Wout = (const float*)d_in[8];
    const float* bout = (const float*)d_in[9];
    const float* drop = (const float*)d_in[10];

    char* ws = (char*)d_ws;
    // workspace layout (bytes), total 162,422,784
    unsigned short* xb  = (unsigned short*)(ws);              // 67,108,864
    unsigned short* wb  = (unsigned short*)(ws + 67108864);   // 25,165,824
    unsigned short* wsb = (unsigned short*)(ws + 92274688);   //  2,621,440
    unsigned short* mhh = (unsigned short*)(ws + 94896128);   //    104,448 (2 buf)
    unsigned short* mhl = (unsigned short*)(ws + 95000576);   //    104,448 (2 buf)
    float*          mcb = (float*)(ws + 95105024);            //    208,896 (2 buf)
    float*          Hs  = (float*)(ws + 95313920);            // 16,777,216
    unsigned short* PI  = (unsigned short*)(ws + 112091136);  // 50,331,648
    float* out = (float*)d_out;

    k_cvt<<<2048, 256, 0, stream>>>(x, xb, (TB * DIN) / 4);
    k_cvt<<<1024, 256, 0, stream>>>(Win, wb, (SIXH * DIN) / 4);
    k_cvt<<<320, 256, 0, stream>>>(Wst, wsb, (FIVEH * HD) / 4);

    k_gemm_pi<<<dim3(SIXH / 128, TB / 128), 256, 0, stream>>>(xb, wb, bin, PI);

    void* args[] = {(void*)&rel, (void*)&h0, (void*)&c0, (void*)&PI,
                    (void*)&wsb, (void*)&bst, (void*)&drop,
                    (void*)&mhh, (void*)&mhl, (void*)&mcb, (void*)&Hs};
    hipLaunchCooperativeKernel(k_recur, dim3(32), dim3(256), args, 0, stream);

    k_pred<<<512, 256, 0, stream>>>(Hs, Wout, bout, out);
}

// Round 3
// 2403.437 us; speedup vs baseline: 2.0268x; 1.4044x over previous
//
#include <hip/hip_runtime.h>
#include <stdint.h>

#define T_STEPS 256
#define BATCH   32
#define DIN     4096
#define HD      512
#define NREL    51
#define TB      8192      // T*B
#define SIXH    3072
#define FIVEH   2560
#define SREL    (NREL * HD)
#define PIWG    786432    // per-WG PI2 block (elems) = TB*6*16

typedef short bf16x8 __attribute__((ext_vector_type(8)));
typedef float f32x4  __attribute__((ext_vector_type(4)));

typedef __attribute__((address_space(1))) const void gvoid_t;
typedef __attribute__((address_space(3))) void lvoid_t;

__device__ inline float bf2f(unsigned short u) {
    return __uint_as_float(((unsigned int)u) << 16);
}
__device__ inline unsigned short f2bf(float f) {
    unsigned int x = __float_as_uint(f);
    x += 0x7fffu + ((x >> 16) & 1u);   // RNE
    return (unsigned short)(x >> 16);
}
__device__ inline float sigm(float x) { return 1.f / (1.f + expf(-x)); }

__device__ inline void gll16(const void* g, void* l) {
    __builtin_amdgcn_global_load_lds((gvoid_t*)g, (lvoid_t*)l, 16, 0, 0);
}

// ---------- phase 0: fp32 -> bf16 converts / flag zero ----------
__global__ void k_cvt(const float* __restrict__ s, unsigned short* __restrict__ d, int n4) {
    int i = blockIdx.x * blockDim.x + threadIdx.x;
    int st = gridDim.x * blockDim.x;
    for (; i < n4; i += st) {
        float4 v = ((const float4*)s)[i];
        ushort4 o;
        o.x = f2bf(v.x); o.y = f2bf(v.y); o.z = f2bf(v.z); o.w = f2bf(v.w);
        ((ushort4*)d)[i] = o;
    }
}

__global__ void k_zero(int* __restrict__ p, int n) {
    int i = blockIdx.x * blockDim.x + threadIdx.x;
    if (i < n) p[i] = 0;
}

// ---------- phase 1: PI2 = x @ W_in^T + b_in, written in per-WG layout ----------
__global__ __launch_bounds__(256) void k_gemm_pi(const unsigned short* __restrict__ xb,
                                                 const unsigned short* __restrict__ wb,
                                                 const float* __restrict__ bin,
                                                 unsigned short* __restrict__ PI2) {
    __shared__ unsigned short sA[128 * 32];
    __shared__ unsigned short sB[128 * 32];
    const int tid = threadIdx.x;
    const int w = tid >> 6, l = tid & 63;
    const int wr = w >> 1, wc = w & 1;
    const long brow = (long)blockIdx.y * 128;
    const long bcol = (long)blockIdx.x * 128;

    f32x4 acc[4][4] = {};

    const int c0 = w * 128 + l;
    const int r0 = c0 >> 2, kc0 = (c0 & 3) * 8;
    const int c1 = c0 + 64;
    const int r1 = c1 >> 2, kc1 = (c1 & 3) * 8;
    unsigned short* lds0A = sA + (w * 128) * 8;
    unsigned short* lds1A = sA + (w * 128 + 64) * 8;
    unsigned short* lds0B = sB + (w * 128) * 8;
    unsigned short* lds1B = sB + (w * 128 + 64) * 8;

    const int frow = l & 15, kg = (l >> 4) * 8;

    for (int k0 = 0; k0 < DIN; k0 += 32) {
        __syncthreads();
        gll16(xb + (brow + r0) * DIN + k0 + kc0, lds0A);
        gll16(xb + (brow + r1) * DIN + k0 + kc1, lds1A);
        gll16(wb + (bcol + r0) * DIN + k0 + kc0, lds0B);
        gll16(wb + (bcol + r1) * DIN + k0 + kc1, lds1B);
        __syncthreads();
        bf16x8 aF[4], bF[4];
#pragma unroll
        for (int m = 0; m < 4; ++m)
            aF[m] = *(const bf16x8*)(sA + (wr * 64 + m * 16 + frow) * 32 + kg);
#pragma unroll
        for (int n = 0; n < 4; ++n)
            bF[n] = *(const bf16x8*)(sB + (wc * 64 + n * 16 + frow) * 32 + kg);
#pragma unroll
        for (int m = 0; m < 4; ++m)
#pragma unroll
            for (int n = 0; n < 4; ++n)
                acc[m][n] = __builtin_amdgcn_mfma_f32_16x16x32_bf16(aF[m], bF[n], acc[m][n], 0, 0, 0);
    }

#pragma unroll
    for (int m = 0; m < 4; ++m) {
#pragma unroll
        for (int n = 0; n < 4; ++n) {
            const long col = bcol + wc * 64 + n * 16 + (l & 15);
            const float bv = bin[col];
            const int g = (int)(col >> 9);
            const int cc = (int)(col & 511);
            const size_t base = (size_t)(cc >> 4) * PIWG + (size_t)(g * 16 + (cc & 15));
#pragma unroll
            for (int r = 0; r < 4; ++r) {
                const long row = brow + wr * 64 + m * 16 + (l >> 4) * 4 + r;
                PI2[base + (size_t)row * 96] = f2bf(acc[m][n][r] + bv);
            }
        }
    }
}

// ---------- phase 2: persistent recurrence, hand-rolled coherent barrier ----------
__global__ __launch_bounds__(256, 1) void k_recur(
    const int* __restrict__ rel, const float* __restrict__ h0,
    const float* __restrict__ c0, const unsigned short* __restrict__ PI2,
    const unsigned short* __restrict__ wsb, const float* __restrict__ bst,
    const float* __restrict__ drop, unsigned int* __restrict__ Hp,
    int* __restrict__ flags, float* __restrict__ Hs)
{
    __shared__ unsigned short Wl[5 * 16 * 512];    // 80 KB, XOR-swizzled
    __shared__ unsigned short piB[2][3072];        // 12 KB PI slabs (dbuf)
    __shared__ int relS[T_STEPS * BATCH];          // 32 KB
    __shared__ unsigned long long pref[T_STEPS];   // 2 KB parity masks
    __shared__ float cS[NREL * 16];                // 3.25 KB c state
    __shared__ float red[2][5][256];               // 10 KB

    const int tid = threadIdx.x;
    const int w = tid >> 6, l = tid & 63;
    const int bid = blockIdx.x;
    const int hc0 = bid * 16;
    const unsigned short* slabBase = PI2 + (size_t)bid * PIWG;

    for (int i = tid; i < T_STEPS * BATCH; i += 256) relS[i] = rel[i];
    __syncthreads();

    // per-step XOR flip masks -> prefix (parity before step t)
    {
        const int t = tid;  // 256 threads, 256 steps
        unsigned long long f = 0;
        for (int b = 0; b < BATCH; ++b) f ^= 1ull << relS[t * BATCH + b];
        pref[t] = f;
    }
    __syncthreads();
    if (tid == 0) {
        unsigned long long run = 0;
        for (int t = 0; t < T_STEPS; ++t) {
            unsigned long long f = pref[t];
            pref[t] = run;
            run ^= f;
        }
    }

    // stage W_state slice into LDS, swizzled: byte ^= (row&7)<<4
    for (int i = tid; i < (5 * 16 * 512) / 8; i += 256) {
        const int k8 = i & 63, gc = i >> 6, c = gc & 15, g = gc >> 4;
        const bf16x8 v = *(const bf16x8*)(wsb + (size_t)(g * HD + hc0 + c) * HD + k8 * 8);
        const int byte = ((gc * 512 + k8 * 8) * 2) ^ ((c & 7) << 4);
        *(bf16x8*)((char*)Wl + byte) = v;
    }

    // init c (LDS) and h parity-0 (global, coherent stores)
    for (int i = tid; i < NREL * 16; i += 256) {
        const int r = i >> 4, c = hc0 + (i & 15);
        cS[i] = c0[r * HD + c];
        const float hv = h0[r * HD + c];
        const unsigned short hi = f2bf(hv);
        const unsigned short lo = f2bf(hv - bf2f(hi));
        const unsigned int pk = ((unsigned int)hi << 16) | lo;
        __hip_atomic_store(&Hp[r * HD + c], pk, __ATOMIC_RELAXED, __HIP_MEMORY_SCOPE_AGENT);
    }

    // prefetch PI slab 0
    gll16(slabBase + (w * 64 + l) * 8, &piB[0][0] + w * 512);
    if (w < 2) gll16(slabBase + (256 + w * 64 + l) * 8, &piB[0][0] + 2048 + w * 512);

    const int m = w & 1, kh = w >> 1;
    const int col = hc0 + (l & 15);
    float bs0 = 0, bs1 = 0, bs2 = 0, bs3 = 0, bs4 = 0;
    float dropv[4] = {};
    if (w < 2) {
        bs0 = bst[col]; bs1 = bst[HD + col]; bs2 = bst[2 * HD + col];
        bs3 = bst[3 * HD + col]; bs4 = bst[4 * HD + col];
#pragma unroll
        for (int r = 0; r < 4; ++r)
            dropv[r] = drop[(w * 16 + (l >> 4) * 4 + r) * HD + col];
    }

    // initial barrier: publish init (target 1)
    {
        __syncthreads();   // drains vmcnt per wave (release for the h stores)
        if (w == 0) {
            if (l == 0) __hip_atomic_store(&flags[bid * 16], 1, __ATOMIC_RELAXED, __HIP_MEMORY_SCOPE_AGENT);
            if (l < 32)
                while (__hip_atomic_load(&flags[l * 16], __ATOMIC_RELAXED, __HIP_MEMORY_SCOPE_AGENT) < 1) {}
        }
        __syncthreads();
    }

    for (int t = 0; t < T_STEPS; ++t) {
        const unsigned long long pm = pref[t];

        // prefetch next PI slab into the other LDS half
        if (t + 1 < T_STEPS) {
            const unsigned short* g = slabBase + (size_t)(t + 1) * 3072;
            unsigned short* dst = &piB[(t + 1) & 1][0];
            gll16(g + (w * 64 + l) * 8, dst + w * 512);
            if (w < 2) gll16(g + (256 + w * 64 + l) * 8, dst + 2048 + w * 512);
        }

        // gather h rows (coherent loads, packed hi|lo)
        const int b = m * 16 + (l & 15);
        const int id = relS[t * BATCH + b];
        const unsigned int* hrow = Hp + (int)((pm >> id) & 1) * SREL + id * HD + kh * 256 + (l >> 4) * 8;
        unsigned long long rw[32];
#pragma unroll
        for (int kk = 0; kk < 8; ++kk) {
            const unsigned long long* p8 = (const unsigned long long*)(hrow + kk * 32);
#pragma unroll
            for (int j = 0; j < 4; ++j)
                rw[kk * 4 + j] = __hip_atomic_load(&p8[j], __ATOMIC_RELAXED, __HIP_MEMORY_SCOPE_AGENT);
        }

        // unpack to hi/lo bf16x8 fragments
        bf16x8 ah[8], al[8];
#pragma unroll
        for (int kk = 0; kk < 8; ++kk) {
            union { unsigned int u[4]; bf16x8 v; } ch, cl;
#pragma unroll
            for (int j = 0; j < 4; ++j) {
                const unsigned int w0 = (unsigned int)rw[kk * 4 + j];
                const unsigned int w1 = (unsigned int)(rw[kk * 4 + j] >> 32);
                ch.u[j] = (w0 >> 16) | (w1 & 0xFFFF0000u);
                cl.u[j] = (w0 & 0xFFFFu) | (w1 << 16);
            }
            ah[kk] = ch.v; al[kk] = cl.v;
        }

        // MFMA: 5 gates, hi+lo A passes
        f32x4 acc[5] = {};
#pragma unroll
        for (int kk = 0; kk < 8; ++kk) {
            const int kb2 = (kh * 256 + kk * 32 + (l >> 4) * 8) * 2;
#pragma unroll
            for (int g = 0; g < 5; ++g) {
                const int byte = (((g * 16 + (l & 15)) * 1024) + kb2) ^ ((l & 7) << 4);
                const bf16x8 bh = *(const bf16x8*)((const char*)Wl + byte);
                acc[g] = __builtin_amdgcn_mfma_f32_16x16x32_bf16(ah[kk], bh, acc[g], 0, 0, 0);
                acc[g] = __builtin_amdgcn_mfma_f32_16x16x32_bf16(al[kk], bh, acc[g], 0, 0, 0);
            }
        }

        if (kh == 1) {
#pragma unroll
            for (int g = 0; g < 5; ++g) *(f32x4*)&red[m][g][l * 4] = acc[g];
        }
        __syncthreads();   // also drains PI slab DMA for this step

        if (w < 2) {
            float ps[5][4];
#pragma unroll
            for (int g = 0; g < 5; ++g) {
                const f32x4 s1 = *(const f32x4*)&red[w][g][l * 4];
#pragma unroll
                for (int r = 0; r < 4; ++r) ps[g][r] = acc[g][r] + s1[r];
            }
            const unsigned short* pb = &piB[t & 1][0];
#pragma unroll
            for (int r = 0; r < 4; ++r) {
                const int b2 = w * 16 + (l >> 4) * 4 + r;
                const int grow = t * BATCH + b2;
                const int id2 = relS[grow];
                const unsigned short* pr = pb + b2 * 96 + (l & 15);
                const float pii = bf2f(pr[0]);
                const float pif = bf2f(pr[16]);
                const float pig = bf2f(pr[32]);
                const float pio = bf2f(pr[48]);
                const float piw = bf2f(pr[64]);
                const float pip = bf2f(pr[80]);
                const float ig = sigm(pii + ps[0][r] + bs0);
                const float fg = sigm(pif + ps[1][r] + bs1);
                const float gg = tanhf(pig + ps[2][r] + bs2);
                const float og = sigm(pio + ps[3][r] + bs3);
                const float hw = sigm(piw + ps[4][r] + bs4);
                const float cp = cS[id2 * 16 + (l & 15)];
                const float cn = ig * gg + fg * cp;
                float h = og * tanhf(cn);
                h = hw * h + (1.f - hw) * pip;
                h *= dropv[r];
                cS[id2 * 16 + (l & 15)] = cn;
                const unsigned short hhi = f2bf(h);
                const unsigned short hlo = f2bf(h - bf2f(hhi));
                const unsigned int pk = ((unsigned int)hhi << 16) | hlo;
                const int pw = (int)(((pm >> id2) & 1) ^ 1ull);
                __hip_atomic_store(&Hp[pw * SREL + id2 * HD + col], pk,
                                   __ATOMIC_RELAXED, __HIP_MEMORY_SCOPE_AGENT);
                Hs[(size_t)grow * HD + col] = h;
            }
        }

        // barrier: publish step t (target t+2)
        __syncthreads();   // per-wave vmcnt(0) drains the coherent h stores
        if (w == 0) {
            if (l == 0) __hip_atomic_store(&flags[bid * 16], t + 2, __ATOMIC_RELAXED, __HIP_MEMORY_SCOPE_AGENT);
            if (l < 32)
                while (__hip_atomic_load(&flags[l * 16], __ATOMIC_RELAXED, __HIP_MEMORY_SCOPE_AGENT) < t + 2) {}
        }
        __syncthreads();
    }
}

// ---------- phase 3: preds = Hs @ W_out^T + b_out (fp32) ----------
__global__ __launch_bounds__(256) void k_pred(const float* __restrict__ Hs,
                                              const float* __restrict__ Wout,
                                              const float* __restrict__ bout,
                                              float* __restrict__ out) {
    __shared__ float hT[16 * HD];
    const int tid = threadIdx.x;
    const long row0 = (long)blockIdx.x * 16;
    for (int i = tid; i < (16 * HD) / 4; i += 256)
        ((float4*)hT)[i] = ((const float4*)(Hs + row0 * HD))[i];
    __syncthreads();
    const int w = tid >> 6, c = tid & 63;
    if (c < NREL) {
        float a0 = bout[c], a1 = a0, a2 = a0, a3 = a0;
        const float* wrp = Wout + c * HD;
        for (int k = 0; k < HD; k += 4) {
            const float4 wv = *(const float4*)(wrp + k);
            const float4 h0 = *(const float4*)(hT + (w * 4 + 0) * HD + k);
            const float4 h1 = *(const float4*)(hT + (w * 4 + 1) * HD + k);
            const float4 h2 = *(const float4*)(hT + (w * 4 + 2) * HD + k);
            const float4 h3 = *(const float4*)(hT + (w * 4 + 3) * HD + k);
            a0 += wv.x * h0.x + wv.y * h0.y + wv.z * h0.z + wv.w * h0.w;
            a1 += wv.x * h1.x + wv.y * h1.y + wv.z * h1.z + wv.w * h1.w;
            a2 += wv.x * h2.x + wv.y * h2.y + wv.z * h2.z + wv.w * h2.w;
            a3 += wv.x * h3.x + wv.y * h3.y + wv.z * h3.z + wv.w * h3.w;
        }
        out[(row0 + w * 4 + 0) * NREL + c] = a0;
        out[(row0 + w * 4 + 1) * NREL + c] = a1;
        out[(row0 + w * 4 + 2) * NREL + c] = a2;
        out[(row0 + w * 4 + 3) * NREL + c] = a3;
    }
}

extern "C" void kernel_launch(void* const* d_in, const int* in_sizes, int n_in,
                              void* d_out, int out_size, void* d_ws, size_t ws_size,
                              hipStream_t stream) {
    const float* x    = (const float*)d_in[0];
    const int*   rel  = (const int*)  d_in[1];
    const float* h0   = (const float*)d_in[2];
    const float* c0   = (const float*)d_in[3];
    const float* Win  = (const float*)d_in[4];
    const float* bin  = (const float*)d_in[5];
    const float* Wst  = (const float*)d_in[6];
    const float* bst  = (const float*)d_in[7];
    const float* Wout = (const float*)d_in[8];
    const float* bout = (const float*)d_in[9];
    const float* drop = (const float*)d_in[10];

    char* ws = (char*)d_ws;
    // workspace layout (bytes), total 162,215,936
    unsigned short* xb   = (unsigned short*)(ws);              // 67,108,864
    unsigned short* wb   = (unsigned short*)(ws + 67108864);   // 25,165,824
    unsigned short* wsb  = (unsigned short*)(ws + 92274688);   //  2,621,440
    unsigned short* PI2  = (unsigned short*)(ws + 94896128);   // 50,331,648
    unsigned int*   Hp   = (unsigned int*)  (ws + 145227776);  //    208,896 (2 parities)
    float*          Hs   = (float*)         (ws + 145436672);  // 16,777,216
    int*            flags= (int*)           (ws + 162213888);  //      2,048
    float* out = (float*)d_out;

    k_zero<<<2, 256, 0, stream>>>(flags, 512);
    k_cvt<<<2048, 256, 0, stream>>>(x, xb, (TB * DIN) / 4);
    k_cvt<<<1024, 256, 0, stream>>>(Win, wb, (SIXH * DIN) / 4);
    k_cvt<<<320, 256, 0, stream>>>(Wst, wsb, (FIVEH * HD) / 4);

    k_gemm_pi<<<dim3(SIXH / 128, TB / 128), 256, 0, stream>>>(xb, wb, bin, PI2);

    void* args[] = {(void*)&rel, (void*)&h0, (void*)&c0, (void*)&PI2,
                    (void*)&wsb, (void*)&bst, (void*)&drop,
                    (void*)&Hp, (void*)&flags, (void*)&Hs};
    hipLaunchCooperativeKernel(k_recur, dim3(32), dim3(256), args, 0, stream);

    k_pred<<<512, 256, 0, stream>>>(Hs, Wout, bout, out);
}